// Round 2
// baseline (155.083 us; speedup 1.0000x reference)
//
#include <hip/hip_runtime.h>
#include <stdint.h>

#define B_ 2
#define L_ 2048
#define DM 1024
#define NH 16
#define DH 64
#define M_ (B_*L_)     // 4096
#define KP 1152        // padded k-row count for P / MT (9 tiles of 128)

typedef short short8 __attribute__((ext_vector_type(8)));
typedef float f32x4 __attribute__((ext_vector_type(4)));

__device__ __forceinline__ unsigned short f2b(float f) {
    union { float f; unsigned int u; } v; v.f = f;
    unsigned int u = v.u;
    return (unsigned short)((u + 0x7fffu + ((u >> 16) & 1u)) >> 16);   // RNE
}

__device__ __forceinline__ float b2f(unsigned short b) {
    union { float f; unsigned int u; } v; v.u = ((unsigned)b) << 16;
    return v.f;
}

__device__ __forceinline__ void gld_lds16(const void* g, void* l) {
    __builtin_amdgcn_global_load_lds(
        (const __attribute__((address_space(1))) void*)g,
        (__attribute__((address_space(3))) void*)l, 16, 0, 0);
}

// ---------------- fused setup --------------------------------------------------
// blocks [0,2048):       x -> bf16 (xb)
// [2048,5120):           transpose Wk(x0.125)/Wv -> WkvT (head-interleaved), Wo -> WoT
// [5120,5632):           Wq -> bf16 natural layout (WqA rows 0..1023)
// [5632,5696):           WqA row 1024 = bq, rows 1025..1151 = 0
// [5696,5698):           biaskv (scaled bk | bv, head-interleaved)
// [5698,5826):           zero KtV
__global__ __launch_bounds__(256)
void setup_kernel(const float* __restrict__ x,
                  const float* __restrict__ Wq, const float* __restrict__ Wk,
                  const float* __restrict__ Wv, const float* __restrict__ Wo,
                  const float* __restrict__ bq, const float* __restrict__ bk,
                  const float* __restrict__ bv,
                  unsigned short* __restrict__ xb, unsigned short* __restrict__ WkvT,
                  unsigned short* __restrict__ WoT, unsigned short* __restrict__ WqA,
                  float* __restrict__ biaskv, float* __restrict__ KtV)
{
    __shared__ float tile[32][33];
    const int bid = blockIdx.x;
    const int t = threadIdx.x;

    if (bid < 2048) {
        int i = (bid * 256 + t) * 8;
        float4 a0 = *(const float4*)(x + i);
        float4 a1 = *(const float4*)(x + i + 4);
        uint4 p;
        p.x = (unsigned)f2b(a0.x) | ((unsigned)f2b(a0.y) << 16);
        p.y = (unsigned)f2b(a0.z) | ((unsigned)f2b(a0.w) << 16);
        p.z = (unsigned)f2b(a1.x) | ((unsigned)f2b(a1.y) << 16);
        p.w = (unsigned)f2b(a1.z) | ((unsigned)f2b(a1.w) << 16);
        *(uint4*)(xb + i) = p;
    } else if (bid < 2048 + 3072) {
        int wb = bid - 2048;
        int wi = wb >> 10;                // 0=Wk 1=Wv 2=Wo
        int tid = wb & 1023;
        const float* W = (wi == 0) ? Wk : (wi == 1) ? Wv : Wo;
        float s = (wi == 0) ? 0.125f : 1.0f;
        int n0 = (tid & 31) * 32, k0 = (tid >> 5) * 32;
        int r = t >> 3, c4 = (t & 7) << 2;
        float4 v = *(const float4*)(W + (size_t)(k0 + r) * DM + n0 + c4);
        tile[r][c4+0] = v.x; tile[r][c4+1] = v.y; tile[r][c4+2] = v.z; tile[r][c4+3] = v.w;
        __syncthreads();
        uint2 o;
        o.x = (unsigned)f2b(tile[c4+0][r]*s) | ((unsigned)f2b(tile[c4+1][r]*s) << 16);
        o.y = (unsigned)f2b(tile[c4+2][r]*s) | ((unsigned)f2b(tile[c4+3][r]*s) << 16);
        int f = n0 + r;
        size_t drow;
        unsigned short* dst;
        if (wi == 0)      { dst = WkvT; drow = (f >> 6) * 128 + (f & 63); }
        else if (wi == 1) { dst = WkvT; drow = (f >> 6) * 128 + 64 + (f & 63); }
        else              { dst = WoT;  drow = f; }
        *(uint2*)(dst + drow * DM + k0 + c4) = o;
    } else if (bid < 2048 + 3072 + 512) {
        int i = ((bid - 5120) * 256 + t) * 8;
        float4 a0 = *(const float4*)(Wq + i);
        float4 a1 = *(const float4*)(Wq + i + 4);
        uint4 p;
        p.x = (unsigned)f2b(a0.x) | ((unsigned)f2b(a0.y) << 16);
        p.y = (unsigned)f2b(a0.z) | ((unsigned)f2b(a0.w) << 16);
        p.z = (unsigned)f2b(a1.x) | ((unsigned)f2b(a1.y) << 16);
        p.w = (unsigned)f2b(a1.z) | ((unsigned)f2b(a1.w) << 16);
        *(uint4*)(WqA + i) = p;
    } else if (bid < 2048 + 3072 + 512 + 64) {
        int idx = ((bid - 5632) * 256 + t) * 8;        // 0..131071 over rows 1024..1151
        uint4 p;
        if (idx < 1024) {
            float4 a0 = *(const float4*)(bq + idx);
            float4 a1 = *(const float4*)(bq + idx + 4);
            p.x = (unsigned)f2b(a0.x) | ((unsigned)f2b(a0.y) << 16);
            p.y = (unsigned)f2b(a0.z) | ((unsigned)f2b(a0.w) << 16);
            p.z = (unsigned)f2b(a1.x) | ((unsigned)f2b(a1.y) << 16);
            p.w = (unsigned)f2b(a1.z) | ((unsigned)f2b(a1.w) << 16);
        } else {
            p.x = p.y = p.z = p.w = 0u;
        }
        *(uint4*)(WqA + 1024 * 1024 + idx) = p;
    } else if (bid < 2048 + 3072 + 512 + 64 + 2) {
        int i = ((bid - 5696) * 256 + t) * 4;
        float o0, o1, o2, o3;
        {
            int n = i + 0, kv = n >> 7, rr = n & 127;
            o0 = (rr < 64) ? 0.125f * bk[kv * 64 + rr] : bv[kv * 64 + (rr - 64)];
        }
        {
            int n = i + 1, kv = n >> 7, rr = n & 127;
            o1 = (rr < 64) ? 0.125f * bk[kv * 64 + rr] : bv[kv * 64 + (rr - 64)];
        }
        {
            int n = i + 2, kv = n >> 7, rr = n & 127;
            o2 = (rr < 64) ? 0.125f * bk[kv * 64 + rr] : bv[kv * 64 + (rr - 64)];
        }
        {
            int n = i + 3, kv = n >> 7, rr = n & 127;
            o3 = (rr < 64) ? 0.125f * bk[kv * 64 + rr] : bv[kv * 64 + (rr - 64)];
        }
        *(float4*)(biaskv + i) = make_float4(o0, o1, o2, o3);
    } else {
        int i = ((bid - 5698) * 256 + t) * 4;
        float4 z; z.x = z.y = z.z = z.w = 0.f;
        *(float4*)(KtV + i) = z;
    }
}

// ---------------- KV projection + K^T V epilogue (proven structure, N=2048) ----
__global__ __launch_bounds__(256)
void kv_fused_kernel(const unsigned short* __restrict__ A,
                     const unsigned short* __restrict__ Bt,
                     const float* __restrict__ biaskv,
                     float* __restrict__ KtV)
{
    __shared__ __align__(16) char smem[34816];
    unsigned short* As = (unsigned short*)smem;
    unsigned short* Bs = (unsigned short*)(smem + 8192);

    const int bid = blockIdx.x;
    const int xcd = bid & 7, local = bid >> 3;    // 64 blocks per XCD
    const int mt = xcd * 4 + (local & 3);         // 0..31
    const int nt = local >> 2;                    // 0..15  (head index)
    const int m0 = mt * 128, n0 = nt * 128;

    const int t = threadIdx.x;
    const int w = t >> 6, lane = t & 63;
    const int quad = lane >> 4, l16 = lane & 15;
    const int wm = w >> 1, wn = w & 1;

    f32x4 acc[4][4];
    #pragma unroll
    for (int i = 0; i < 4; i++)
        #pragma unroll
        for (int j = 0; j < 4; j++)
            #pragma unroll
            for (int r = 0; r < 4; r++) acc[i][j][r] = 0.f;

    const int srow = t >> 2;
    const int schunk = t & 3;

    for (int kk = 0; kk < DM; kk += 32) {
        #pragma unroll
        for (int p = 0; p < 2; p++) {
            int row = p * 64 + srow;
            int g = schunk ^ ((row >> 1) & 3);
            gld_lds16(A  + (size_t)(m0 + row) * DM + kk + g * 8,
                      (char*)As + p * 4096 + w * 1024);
            gld_lds16(Bt + (size_t)(n0 + row) * DM + kk + g * 8,
                      (char*)Bs + p * 4096 + w * 1024);
        }
        __syncthreads();

        short8 afr[4], bfr[4];
        #pragma unroll
        for (int i = 0; i < 4; i++) {
            int am = wm * 64 + i * 16 + l16;
            afr[i] = *(const short8*)((const char*)As + am * 64 + ((quad ^ ((am >> 1) & 3)) << 4));
            int bn = wn * 64 + i * 16 + l16;
            bfr[i] = *(const short8*)((const char*)Bs + bn * 64 + ((quad ^ ((bn >> 1) & 3)) << 4));
        }
        #pragma unroll
        for (int i = 0; i < 4; i++)
            #pragma unroll
            for (int j = 0; j < 4; j++)
                acc[i][j] = __builtin_amdgcn_mfma_f32_16x16x32_bf16(afr[i], bfr[j], acc[i][j], 0, 0, 0);
        __syncthreads();
    }

    #pragma unroll
    for (int j = 0; j < 4; j++) {
        float bvv = biaskv[n0 + wn * 64 + j * 16 + l16];
        #pragma unroll
        for (int i = 0; i < 4; i++)
            #pragma unroll
            for (int r = 0; r < 4; r++) acc[i][j][r] += bvv;
    }

    // ---- head h = nt; tile cols 0..63 = K_h, 64..127 = V_h -> KtV atomics ----
    const int h  = nt;
    const int bh = (m0 >> 11) * NH + h;
    unsigned short (*Xt)[136] = (unsigned short (*)[136])smem;   // [c][l]

    #pragma unroll
    for (int j = 0; j < 4; j++) {
        int c = wn * 64 + j * 16 + l16;
        #pragma unroll
        for (int i = 0; i < 4; i++) {
            int l0 = wm * 64 + i * 16 + quad * 4;
            uint2 o;
            o.x = (unsigned)f2b(acc[i][j][0]) | ((unsigned)f2b(acc[i][j][1]) << 16);
            o.y = (unsigned)f2b(acc[i][j][2]) | ((unsigned)f2b(acc[i][j][3]) << 16);
            *(uint2*)&Xt[c][l0] = o;
        }
    }
    __syncthreads();

    f32x4 kacc[4];
    #pragma unroll
    for (int j = 0; j < 4; j++)
        #pragma unroll
        for (int r = 0; r < 4; r++) kacc[j][r] = 0.f;

    #pragma unroll
    for (int ks = 0; ks < 4; ks++) {
        short8 af = *(const short8*)&Xt[w * 16 + l16][ks * 32 + quad * 8];
        #pragma unroll
        for (int j = 0; j < 4; j++) {
            short8 bfr = *(const short8*)&Xt[64 + j * 16 + l16][ks * 32 + quad * 8];
            kacc[j] = __builtin_amdgcn_mfma_f32_16x16x32_bf16(af, bfr, kacc[j], 0, 0, 0);
        }
    }

    float* dst = KtV + (size_t)bh * 64 * 64;
    #pragma unroll
    for (int j = 0; j < 4; j++) {
        int col = j * 16 + l16;
        #pragma unroll
        for (int r = 0; r < 4; r++) {
            int row = w * 16 + quad * 4 + r;
            atomicAdd(dst + row * 64 + col, kacc[j][r]);
        }
    }
}

// ---------------- P[b][k][h*64+d2] = sum_d1 WqA[k][h*64+d1] * KtV[bh][d1][d2] --
// k runs 0..1151 (row 1024 = bq row -> bias fold; rows 1025+ zero)
__global__ __launch_bounds__(256)
void pmat_kernel(const unsigned short* __restrict__ WqA, const float* __restrict__ KtV,
                 unsigned short* __restrict__ P)
{
    __shared__ __align__(16) unsigned short As[128 * 64];   // swizzled, 16 KB
    __shared__ __align__(16) unsigned short Bs[64][72];     // Bt[d2][d1] = KtV^T

    const int bh = blockIdx.x;        // 0..31
    const int rt = blockIdx.y;        // 0..8
    const int b = bh >> 4, h = bh & 15;
    const int t = threadIdx.x;
    const int w = t >> 6, lane = t & 63;
    const int quad = lane >> 4, l16 = lane & 15;

    #pragma unroll
    for (int p = 0; p < 4; p++) {
        int c = p * 256 + t;
        int row = c >> 3, slot = c & 7;
        int g = slot ^ ((row >> 1) & 7);
        gld_lds16(WqA + (size_t)(rt * 128 + row) * DM + h * 64 + g * 8,
                  (char*)As + p * 4096 + w * 1024);
    }
    {
        const int d1 = t >> 2, c0 = (t & 3) * 16;
        const float* kp = KtV + (size_t)bh * 64 * 64 + d1 * 64 + c0;
        #pragma unroll
        for (int j = 0; j < 16; j++)
            Bs[c0 + j][d1] = f2b(kp[j]);
    }
    __syncthreads();

    f32x4 acc[2][4];
    #pragma unroll
    for (int i = 0; i < 2; i++)
        #pragma unroll
        for (int j = 0; j < 4; j++)
            #pragma unroll
            for (int r = 0; r < 4; r++) acc[i][j][r] = 0.f;

    #pragma unroll
    for (int ks = 0; ks < 2; ks++) {
        int kc = ks * 4 + quad;
        short8 afr[2], bfr[4];
        #pragma unroll
        for (int i = 0; i < 2; i++) {
            int am = w * 32 + i * 16 + l16;
            afr[i] = *(const short8*)((const char*)As + am * 128 + ((kc ^ ((am >> 1) & 7)) << 4));
        }
        #pragma unroll
        for (int j = 0; j < 4; j++)
            bfr[j] = *(const short8*)&Bs[j * 16 + l16][ks * 32 + quad * 8];
        #pragma unroll
        for (int i = 0; i < 2; i++)
            #pragma unroll
            for (int j = 0; j < 4; j++)
                acc[i][j] = __builtin_amdgcn_mfma_f32_16x16x32_bf16(afr[i], bfr[j], acc[i][j], 0, 0, 0);
    }

    unsigned short* pb = P + ((size_t)b * KP + rt * 128) * DM + h * 64;
    #pragma unroll
    for (int j = 0; j < 4; j++) {
        int col = j * 16 + l16;
        #pragma unroll
        for (int i = 0; i < 2; i++)
            #pragma unroll
            for (int rr = 0; rr < 4; rr++) {
                int row = w * 32 + i * 16 + quad * 4 + rr;
                pb[(size_t)row * DM + col] = f2b(acc[i][j][rr]);
            }
    }
}

// ---------------- MT[b][n][k] = sum_f WoT[n][f] * P[b][k][f] -------------------
__global__ __launch_bounds__(256)
void mmat_kernel(const unsigned short* __restrict__ WoT, const unsigned short* __restrict__ P,
                 unsigned short* __restrict__ MT)
{
    __shared__ __align__(16) unsigned short As[128 * 64];   // 16 KB
    __shared__ __align__(16) unsigned short Bs[64 * 64];    // 8 KB

    const int bid = blockIdx.x;
    const int bb = bid / 144;
    const int r144 = bid % 144;
    const int mt = r144 & 7, nt = r144 >> 3;   // n-tile 0..7, k-tile 0..17
    const int m0 = mt * 128, n0 = nt * 64;

    const int t = threadIdx.x;
    const int w = t >> 6, lane = t & 63;
    const int quad = lane >> 4, l16 = lane & 15;

    f32x4 acc[2][4];
    #pragma unroll
    for (int i = 0; i < 2; i++)
        #pragma unroll
        for (int j = 0; j < 4; j++)
            #pragma unroll
            for (int r = 0; r < 4; r++) acc[i][j][r] = 0.f;

    for (int kk = 0; kk < DM; kk += 64) {
        #pragma unroll
        for (int p = 0; p < 4; p++) {
            int c = p * 256 + t;
            int row = c >> 3, slot = c & 7;
            int g = slot ^ ((row >> 1) & 7);
            gld_lds16(WoT + (size_t)(m0 + row) * DM + kk + g * 8,
                      (char*)As + p * 4096 + w * 1024);
        }
        #pragma unroll
        for (int p = 0; p < 2; p++) {
            int c = p * 256 + t;
            int row = c >> 3, slot = c & 7;
            int g = slot ^ ((row >> 1) & 7);
            gld_lds16(P + ((size_t)bb * KP + n0 + row) * DM + kk + g * 8,
                      (char*)Bs + p * 4096 + w * 1024);
        }
        __syncthreads();

        #pragma unroll
        for (int ks = 0; ks < 2; ks++) {
            int kc = ks * 4 + quad;
            short8 afr[2], bfr[4];
            #pragma unroll
            for (int i = 0; i < 2; i++) {
                int am = w * 32 + i * 16 + l16;
                afr[i] = *(const short8*)((const char*)As + am * 128 + ((kc ^ ((am >> 1) & 7)) << 4));
            }
            #pragma unroll
            for (int j = 0; j < 4; j++) {
                int bn = j * 16 + l16;
                bfr[j] = *(const short8*)((const char*)Bs + bn * 128 + ((kc ^ ((bn >> 1) & 7)) << 4));
            }
            #pragma unroll
            for (int i = 0; i < 2; i++)
                #pragma unroll
                for (int j = 0; j < 4; j++)
                    acc[i][j] = __builtin_amdgcn_mfma_f32_16x16x32_bf16(afr[i], bfr[j], acc[i][j], 0, 0, 0);
        }
        __syncthreads();
    }

    unsigned short* mb = MT + (size_t)bb * 1024 * KP;
    #pragma unroll
    for (int j = 0; j < 4; j++) {
        int col = n0 + j * 16 + l16;
        #pragma unroll
        for (int i = 0; i < 2; i++)
            #pragma unroll
            for (int rr = 0; rr < 4; rr++) {
                int row = m0 + w * 32 + i * 16 + quad * 4 + rr;
                mb[(size_t)row * KP + col] = f2b(acc[i][j][rr]);
            }
    }
}

// ---------------- out = x @ M_b + (MT col 1024 + bo): 128x64 tile, BK=64 -------
__global__ __launch_bounds__(256)
void out_gemm_kernel(const unsigned short* __restrict__ A,
                     const unsigned short* __restrict__ Bt,    // MT [2][1024][KP]
                     const float* __restrict__ bias,
                     float* __restrict__ C)
{
    __shared__ __align__(16) unsigned short As[128 * 64];   // 16 KB
    __shared__ __align__(16) unsigned short Bs[64 * 64];    // 8 KB

    const int bid = blockIdx.x;
    const int xcd = bid & 7, local = bid >> 3;   // 64 per XCD
    const int mt = xcd * 4 + (local & 3);        // 0..31
    const int nt = local >> 2;                   // 0..15
    const int m0 = mt * 128, n0 = nt * 64;

    const int t = threadIdx.x;
    const int w = t >> 6, lane = t & 63;
    const int quad = lane >> 4, l16 = lane & 15;

    const unsigned short* Btb = Bt + (size_t)(m0 >> 11) * 1024 * KP;

    f32x4 acc[2][4];
    #pragma unroll
    for (int i = 0; i < 2; i++)
        #pragma unroll
        for (int j = 0; j < 4; j++)
            #pragma unroll
            for (int r = 0; r < 4; r++) acc[i][j][r] = 0.f;

    for (int kk = 0; kk < DM; kk += 64) {
        #pragma unroll
        for (int p = 0; p < 4; p++) {              // A: 128 rows x 8 chunks
            int c = p * 256 + t;
            int row = c >> 3, slot = c & 7;
            int g = slot ^ ((row >> 1) & 7);
            gld_lds16(A + (size_t)(m0 + row) * DM + kk + g * 8,
                      (char*)As + p * 4096 + w * 1024);
        }
        #pragma unroll
        for (int p = 0; p < 2; p++) {              // B: 64 rows x 8 chunks
            int c = p * 256 + t;
            int row = c >> 3, slot = c & 7;
            int g = slot ^ ((row >> 1) & 7);
            gld_lds16(Btb + (size_t)(n0 + row) * KP + kk + g * 8,
                      (char*)Bs + p * 4096 + w * 1024);
        }
        __syncthreads();

        #pragma unroll
        for (int ks = 0; ks < 2; ks++) {
            int kc = ks * 4 + quad;
            short8 afr[2], bfr[4];
            #pragma unroll
            for (int i = 0; i < 2; i++) {
                int am = w * 32 + i * 16 + l16;
                afr[i] = *(const short8*)((const char*)As + am * 128 + ((kc ^ ((am >> 1) & 7)) << 4));
            }
            #pragma unroll
            for (int j = 0; j < 4; j++) {
                int bn = j * 16 + l16;
                bfr[j] = *(const short8*)((const char*)Bs + bn * 128 + ((kc ^ ((bn >> 1) & 7)) << 4));
            }
            #pragma unroll
            for (int i = 0; i < 2; i++)
                #pragma unroll
                for (int j = 0; j < 4; j++)
                    acc[i][j] = __builtin_amdgcn_mfma_f32_16x16x32_bf16(afr[i], bfr[j], acc[i][j], 0, 0, 0);
        }
        __syncthreads();
    }

    #pragma unroll
    for (int j = 0; j < 4; j++) {
        int col = n0 + j * 16 + l16;
        float bvv = bias[col] + b2f(Btb[(size_t)col * KP + 1024]);
        #pragma unroll
        for (int i = 0; i < 2; i++) {
            #pragma unroll
            for (int r = 0; r < 4; r++) {
                int row = m0 + w * 32 + i * 16 + quad * 4 + r;
                C[(size_t)row * DM + col] = acc[i][j][r] + bvv;
            }
        }
    }
}

// ---------------- launch ------------------------------------------------------

extern "C" void kernel_launch(void* const* d_in, const int* in_sizes, int n_in,
                              void* d_out, int out_size, void* d_ws, size_t ws_size,
                              hipStream_t stream)
{
    const float* x  = (const float*)d_in[0];
    const float* Wq = (const float*)d_in[1];
    const float* bq = (const float*)d_in[2];
    const float* Wk = (const float*)d_in[3];
    const float* bk = (const float*)d_in[4];
    const float* Wv = (const float*)d_in[5];
    const float* bv = (const float*)d_in[6];
    const float* Wo = (const float*)d_in[7];
    const float* bo = (const float*)d_in[8];

    char* ws = (char*)d_ws;
    unsigned short* xb     = (unsigned short*)(ws);                               // 8 MB
    unsigned short* WkvT   = (unsigned short*)(ws + (size_t)8  * 1024 * 1024);    // 4 MB
    unsigned short* WoT    = (unsigned short*)(ws + (size_t)12 * 1024 * 1024);    // 2 MB
    unsigned short* WqA    = (unsigned short*)(ws + (size_t)14 * 1024 * 1024);    // 2.25 MB
    float*          biaskv = (float*)         (ws + (size_t)16 * 1024 * 1024 + 262144); // 8 KB
    float*          KtV    = (float*)         (ws + (size_t)17 * 1024 * 1024);    // 512 KB
    unsigned short* P      = (unsigned short*)(ws + (size_t)18 * 1024 * 1024);    // 4.5 MB
    unsigned short* MT     = (unsigned short*)(ws + (size_t)23 * 1024 * 1024);    // 4.5 MB

    setup_kernel<<<5826, 256, 0, stream>>>(x, Wq, Wk, Wv, Wo, bq, bk, bv,
                                           xb, WkvT, WoT, WqA, biaskv, KtV);

    kv_fused_kernel<<<512, 256, 0, stream>>>(xb, WkvT, biaskv, KtV);

    pmat_kernel<<<dim3(32, 9), 256, 0, stream>>>(WqA, KtV, P);

    mmat_kernel<<<288, 256, 0, stream>>>(WoT, P, MT);

    out_gemm_kernel<<<512, 256, 0, stream>>>(xb, MT, bo, (float*)d_out);
}